// Round 4
// baseline (300.534 us; speedup 1.0000x reference)
//
#include <hip/hip_runtime.h>
#include <math.h>

#define N 128
#define VOL (N*N*N)            // 2097152
#define PLANE (N*N)            // 16384
#define NKX 65                 // kept x-frequencies 0..64 (Hermitian half)
#define NSHELL 65              // shells 0..64
#define ACC_STRIDE 195         // 3*65 per batch

// packed complex: .x = re, .y = im. Vector ops lower to v_pk_*_f32.
typedef float cplx __attribute__((ext_vector_type(2)));

__device__ __forceinline__ int rev6(int x) { return (int)(__brev((unsigned)x) >> 26); }

// complex multiply by twiddle w=(c,s): r = a*c + swap(a)*(-s, s)
__device__ __forceinline__ cplx cmulw(cplx a, cplx w) {
    cplx sw = __builtin_shufflevector(a, a, 1, 0);
    return __builtin_elementwise_fma(sw, (cplx){-w.y, w.y}, a * w.x);
}

// ---- cross-lane exchange layer (VALU-pipe, no LDS except xor-4) ----
__device__ __forceinline__ void plswap32(cplx v, cplx& lo, cplx& hi) {
    float ax = v.x, bx = v.x, ay = v.y, by = v.y;
    asm("v_permlane32_swap_b32 %0, %1" : "+v"(ax), "+v"(bx));
    asm("v_permlane32_swap_b32 %0, %1" : "+v"(ay), "+v"(by));
    lo = (cplx){ax, ay}; hi = (cplx){bx, by};
}
__device__ __forceinline__ void plswap16(cplx v, cplx& lo, cplx& hi) {
    float ax = v.x, bx = v.x, ay = v.y, by = v.y;
    asm("v_permlane16_swap_b32 %0, %1" : "+v"(ax), "+v"(bx));
    asm("v_permlane16_swap_b32 %0, %1" : "+v"(ay), "+v"(by));
    lo = (cplx){ax, ay}; hi = (cplx){bx, by};
}
template<int CTRL>
__device__ __forceinline__ cplx dpp_xor(cplx v) {
    int rx = __builtin_amdgcn_mov_dpp(__float_as_int(v.x), CTRL, 0xF, 0xF, true);
    int ry = __builtin_amdgcn_mov_dpp(__float_as_int(v.y), CTRL, 0xF, 0xF, true);
    return (cplx){__int_as_float(rx), __int_as_float(ry)};
}
// h=4: no DPP/permlane pattern for xor4 -> ds_swizzle on packed bf16.
// Split into pack-issue / unpack so a K-batch issues ALL swizzles before the
// single lgkmcnt wait (amortizes the ~120cy LDS latency across 2K exchanges).
__device__ __forceinline__ unsigned swz4_issue(cplx v) {
    unsigned p = __builtin_amdgcn_perm(__float_as_uint(v.y), __float_as_uint(v.x), 0x07060302u);
    return (unsigned)__builtin_amdgcn_ds_swizzle((int)p, 0x101F);  // xor 4
}
__device__ __forceinline__ cplx swz4_take(unsigned q) {
    return (cplx){__uint_as_float(q << 16), __uint_as_float(q & 0xFFFF0000u)};
}

// bf16x2 pack (RNE) / unpack: complex value in one uint (re low, im high)
__device__ __forceinline__ unsigned int pack_bf2(cplx v) {
    unsigned int r = __float_as_uint(v.x);
    unsigned int i = __float_as_uint(v.y);
    r = (r + 0x7FFFu + ((r >> 16) & 1u)) >> 16;
    i = (i + 0x7FFFu + ((i >> 16) & 1u)) & 0xFFFF0000u;
    return i | r;
}
__device__ __forceinline__ cplx unpack_bf2(unsigned int u) {
    return (cplx){__uint_as_float(u << 16), __uint_as_float(u & 0xFFFF0000u)};
}

// fp8 e4m3 packed complex (re byte0, im byte1) for the in-LDS plane
__device__ __forceinline__ unsigned short pack_f8(cplx v) {
    int p = __builtin_amdgcn_cvt_pk_fp8_f32(v.x, v.y, 0, false);
    return (unsigned short)(p & 0xFFFF);
}
__device__ __forceinline__ cplx unpack_f8(unsigned short u) {
    auto r = __builtin_amdgcn_cvt_pk_f32_fp8((int)u, false);
    return (cplx){r[0], r[1]};
}

// 64-entry twiddle table W[m] = e^{-2*pi*i*m/128}, built once per block
__device__ __forceinline__ void build_W(cplx* Wsh, int tid) {
    if (tid < 64) {
        float s, c;
        sincosf(-6.283185307179586f * (float)tid / 128.0f, &s, &c);
        Wsh[tid] = (cplx){c, s};
    }
}

struct TwE { cplx w128; cplx we[5]; };

__device__ __forceinline__ TwE make_twe(const cplx* Wsh, int lane) {
    TwE w;
    w.w128 = Wsh[lane];
    #pragma unroll
    for (int i = 0; i < 5; i++) {
        int h = 32 >> i;
        cplx t = Wsh[(lane & (h - 1)) << (i + 1)];
        w.we[i] = (lane & h) ? t : (cplx){1.0f, 0.0f};
    }
    return w;
}

__device__ __forceinline__ void bstage(cplx& v, cplx o, float s, cplx we) {
    cplx t = __builtin_elementwise_fma((cplx){s, s}, v, o);
    v = cmulw(t, we);
}
__device__ __forceinline__ void bstage_lh(cplx& v, cplx lo, cplx hi, float s, cplx we) {
    cplx t = __builtin_elementwise_fma((cplx){s, s}, hi, lo);
    v = cmulw(t, we);
}

// K independent 128-pt DIF FFTs per call (2K dependency chains in flight).
// 5 of 6 cross-lane stages on the VALU pipe (permlane_swap / DPP, fp32
// exact); xor-4 issues all 2K ds_swizzles then one wait.
// For each k: u0[k]=x[lane], u1[k]=x[lane+64] on input;
// u0[k]=X[2*rev6(lane)], u1[k]=X[2*rev6(lane)+1] on output.
template<int K>
__device__ __forceinline__ void fft128v(cplx (&u0)[K], cplx (&u1)[K],
                                        const TwE& w, int lane) {
    #pragma unroll
    for (int k = 0; k < K; k++) {
        cplx d = u0[k] - u1[k];
        u0[k] = u0[k] + u1[k];
        u1[k] = cmulw(d, w.w128);
    }
    {   // h = 32 : permlane32_swap
        float s = (lane & 32) ? -1.0f : 1.0f;
        #pragma unroll
        for (int k = 0; k < K; k++) {
            cplx lo, hi;
            plswap32(u0[k], lo, hi); bstage_lh(u0[k], lo, hi, s, w.we[0]);
            plswap32(u1[k], lo, hi); bstage_lh(u1[k], lo, hi, s, w.we[0]);
        }
    }
    {   // h = 16 : permlane16_swap
        float s = (lane & 16) ? -1.0f : 1.0f;
        #pragma unroll
        for (int k = 0; k < K; k++) {
            cplx lo, hi;
            plswap16(u0[k], lo, hi); bstage_lh(u0[k], lo, hi, s, w.we[1]);
            plswap16(u1[k], lo, hi); bstage_lh(u1[k], lo, hi, s, w.we[1]);
        }
    }
    {   // h = 8 : DPP row_ror:8
        float s = (lane & 8) ? -1.0f : 1.0f;
        #pragma unroll
        for (int k = 0; k < K; k++) {
            bstage(u0[k], dpp_xor<0x128>(u0[k]), s, w.we[2]);
            bstage(u1[k], dpp_xor<0x128>(u1[k]), s, w.we[2]);
        }
    }
    {   // h = 4 : batched ds_swizzle stage (packed bf16), one wait for 2K ops
        float s = (lane & 4) ? -1.0f : 1.0f;
        unsigned q0[K], q1[K];
        #pragma unroll
        for (int k = 0; k < K; k++) { q0[k] = swz4_issue(u0[k]); q1[k] = swz4_issue(u1[k]); }
        #pragma unroll
        for (int k = 0; k < K; k++) {
            bstage(u0[k], swz4_take(q0[k]), s, w.we[3]);
            bstage(u1[k], swz4_take(q1[k]), s, w.we[3]);
        }
    }
    {   // h = 2 : DPP quad_perm [2,3,0,1]
        float s = (lane & 2) ? -1.0f : 1.0f;
        #pragma unroll
        for (int k = 0; k < K; k++) {
            bstage(u0[k], dpp_xor<0x4E>(u0[k]), s, w.we[4]);
            bstage(u1[k], dpp_xor<0x4E>(u1[k]), s, w.we[4]);
        }
    }
    {   // h = 1 : DPP quad_perm [1,0,3,2], final butterfly (no twiddle)
        float s = (lane & 1) ? -1.0f : 1.0f;
        cplx sv = (cplx){s, s};
        #pragma unroll
        for (int k = 0; k < K; k++) {
            u0[k] = __builtin_elementwise_fma(sv, u0[k], dpp_xor<0xB1>(u0[k]));
            u1[k] = __builtin_elementwise_fma(sv, u1[k], dpp_xor<0xB1>(u1[k]));
        }
    }
}

// slot index holding frequency k after fft128
__device__ __forceinline__ int slot_of(int k) {
    return (k & 1) ? 64 + rev6(k >> 1) : rev6(k >> 1);
}

// shell accumulate one (o,t) point at radius^2 r2
__device__ __forceinline__ void acc_pt(float* accn, float* accp, float* accq,
                                       int r2, cplx o, cplx t) {
    if (r2 <= 4224) {
        int sh = (int)sqrtf((float)r2);
        if ((sh + 1) * (sh + 1) <= r2) sh++;
        else if (sh * sh > r2) sh--;
        atomicAdd(&accn[sh], o.x * t.x + o.y * t.y);
        atomicAdd(&accp[sh], o.x * o.x + o.y * o.y);
        atomicAdd(&accq[sh], t.x * t.x + t.y * t.y);
    }
}

// ---- Pass 1: packed x-FFT (L = mo + i*tg), Hermitian unpack, keep kx=0..64 ----
// grid: nb*128(z)*2(ytile) blocks of 1024 (16 waves, 64 y-lines per block).
// One fft128v<4> per wave (4 y-lines, 8 chains in flight). Workspace element
// = uint64 {O:bf16x2 | T:bf16x2 << 32} at [b][kx][z][y]; NT dwordx2 stores in
// 512B runs.
__global__ __launch_bounds__(1024, 8)
void fft_x_pack_kernel(const float* __restrict__ in0, const float* __restrict__ in1,
                       unsigned long long* __restrict__ ws, int b0, float scale)
{
    __shared__ cplx tile[64][129];
    __shared__ cplx Wsh[64];
    int tid = threadIdx.x, lane = tid & 63, wave = tid >> 6;
    int bi = blockIdx.x;
    int yt = bi & 1, z = (bi >> 1) & 127, b = bi >> 8;
    build_W(Wsh, tid);
    __syncthreads();
    TwE w = make_twe(Wsh, lane);

    size_t src_base = (size_t)(b0 + b) * VOL + (size_t)z * PLANE + (size_t)(yt * 64 + wave * 4) * N;
    const float* q0 = in0 + src_base;
    const float* q1 = in1 + src_base;
    cplx u0[4], u1[4];
    #pragma unroll
    for (int r = 0; r < 4; r++) {
        u0[r] = (cplx){q0[r * N + lane]      * scale, q1[r * N + lane]      * scale};
        u1[r] = (cplx){q0[r * N + lane + 64] * scale, q1[r * N + lane + 64] * scale};
    }
    fft128v<4>(u0, u1, w, lane);
    int j0 = wave * 4;
    #pragma unroll
    for (int r = 0; r < 4; r++) {
        tile[j0 + r][lane]      = u0[r];
        tile[j0 + r][lane + 64] = u1[r];
    }
    __syncthreads();

    // unpack: O = (L(k)+conj(L(-k)))/2 ; T = (L(k)-conj(L(-k)))/(2i)
    // j spans 64 consecutive y per wave -> 512B NT store runs.
    size_t dst_off = (size_t)b * NKX * PLANE + (size_t)z * N + yt * 64;
    for (int idx = tid; idx < NKX * 64; idx += 1024) {
        int j  = idx & 63;
        int kx = idx >> 6;               // wave-uniform (waves are 64-aligned)
        int mk = (128 - kx) & 127;
        cplx a  = tile[j][slot_of(kx)];
        cplx bm = tile[j][slot_of(mk)];
        cplx O = (cplx){0.5f * (a.x + bm.x), 0.5f * (a.y - bm.y)};
        cplx T = (cplx){0.5f * (a.y + bm.y), 0.5f * (bm.x - a.x)};
        unsigned long long v = ((unsigned long long)pack_bf2(T) << 32) | (unsigned long long)pack_bf2(O);
        __builtin_nontemporal_store(v, &ws[dst_off + (size_t)kx * PLANE + j]);
    }
}

// ---- Fused pass 2: y-FFT + z-FFT + shell accumulation per (b, kx) plane ----
// grid: nb*64 blocks of 1024 (16 waves); 2 blocks/CU * 256 CUs at nb=8 -> no
// tail. Slot 63 handles BOTH kx=63 and kx=64.
// Phase A: TWO z-lines (4 chains) per fft128v<4>; prefetch next pair.
// Phase B: wave-uniform live mask; live ky lines processed in PAIRS (4 chains).
// LDS plane as fp8x2 (values x16 from pass1's scale; shell sums x256,
// undone at flush). Swizzle col = (z + ky) & 127.
__global__ __launch_bounds__(1024, 8)
void fft_yz_acc_kernel(const unsigned long long* __restrict__ ws, float* __restrict__ gacc,
                       int nb, int b0)
{
    __shared__ unsigned short tile[2][128][128];   // 65536 B
    __shared__ cplx Wsh[64];
    __shared__ float accn[NSHELL], accp[NSHELL], accq[NSHELL];
    int tid = threadIdx.x, lane = tid & 63, wave = tid >> 6;
    int bi = blockIdx.x;
    int kslot = bi / nb;              // 0..63
    int b = bi - kslot * nb;
    int np = (kslot == 63) ? 2 : 1;

    build_W(Wsh, tid);
    __syncthreads();
    TwE w = make_twe(Wsh, lane);

    int kz0 = 2 * rev6(lane), kz1 = kz0 + 1;
    int cz0 = (kz0 < 64) ? kz0 : kz0 - 128;
    int cz1 = (kz1 < 64) ? kz1 : kz1 - 128;
    int z20 = cz0 * cz0, z21 = cz1 * cz1;

    for (int p = 0; p < np; p++) {
        int kx = (kslot < 63) ? kslot : (63 + p);
        if (tid < NSHELL) { accn[tid] = 0.0f; accp[tid] = 0.0f; accq[tid] = 0.0f; }
        __syncthreads();

        // Phase A: 128 z-lines, each u64 carrying {O,T}; wave handles 8,
        // two lines per fft128v<4> call.
        const unsigned long long* pz = ws + ((size_t)b * NKX + kx) * PLANE + (size_t)(wave * 8) * N;
        unsigned long long v00 = __builtin_nontemporal_load(pz + lane);
        unsigned long long v01 = __builtin_nontemporal_load(pz + lane + 64);
        unsigned long long v10 = __builtin_nontemporal_load(pz + N + lane);
        unsigned long long v11 = __builtin_nontemporal_load(pz + N + lane + 64);
        for (int c = 0; c < 8; c += 2) {
            unsigned long long n00 = 0, n01 = 0, n10 = 0, n11 = 0;
            if (c < 6) {   // prefetch next line pair (wave-uniform branch)
                const unsigned long long* q = pz + (size_t)(c + 2) * N;
                n00 = __builtin_nontemporal_load(q + lane);
                n01 = __builtin_nontemporal_load(q + lane + 64);
                n10 = __builtin_nontemporal_load(q + N + lane);
                n11 = __builtin_nontemporal_load(q + N + lane + 64);
            }
            cplx u0[4], u1[4];
            u0[0] = unpack_bf2((unsigned)v00);         u1[0] = unpack_bf2((unsigned)v01);
            u0[1] = unpack_bf2((unsigned)(v00 >> 32)); u1[1] = unpack_bf2((unsigned)(v01 >> 32));
            u0[2] = unpack_bf2((unsigned)v10);         u1[2] = unpack_bf2((unsigned)v11);
            u0[3] = unpack_bf2((unsigned)(v10 >> 32)); u1[3] = unpack_bf2((unsigned)(v11 >> 32));
            fft128v<4>(u0, u1, w, lane);
            int z0 = wave * 8 + c;
            int ky0 = 2 * rev6(lane);                // u1 holds ky0+1
            tile[0][ky0    ][(z0     + ky0    ) & 127] = pack_f8(u0[0]);
            tile[0][ky0 + 1][(z0     + ky0 + 1) & 127] = pack_f8(u1[0]);
            tile[1][ky0    ][(z0     + ky0    ) & 127] = pack_f8(u0[1]);
            tile[1][ky0 + 1][(z0     + ky0 + 1) & 127] = pack_f8(u1[1]);
            tile[0][ky0    ][(z0 + 1 + ky0    ) & 127] = pack_f8(u0[2]);
            tile[0][ky0 + 1][(z0 + 1 + ky0 + 1) & 127] = pack_f8(u1[2]);
            tile[1][ky0    ][(z0 + 1 + ky0    ) & 127] = pack_f8(u0[3]);
            tile[1][ky0 + 1][(z0 + 1 + ky0 + 1) & 127] = pack_f8(u1[3]);
            v00 = n00; v01 = n01; v10 = n10; v11 = n11;
        }
        __syncthreads();

        // Phase B: z-FFT per live ky line + accumulate; lines paired for ILP.
        // Liveness is wave-uniform (ky = wave + 16c).
        int kx2 = kx * kx;
        unsigned mlive = 0;
        #pragma unroll
        for (int c = 0; c < 8; c++) {
            int ky = wave + 16 * c;
            int cy = (ky < 64) ? ky : ky - 128;
            if (kx2 + cy * cy <= 4224) mlive |= 1u << c;
        }
        while (mlive) {
            int cA = __ffs(mlive) - 1; mlive &= mlive - 1;
            int kyA = wave + 16 * cA;
            int cyA = (kyA < 64) ? kyA : kyA - 128;
            int b2A = kx2 + cyA * cyA;
            int cA0 = (lane + kyA) & 127, cA1 = (lane + 64 + kyA) & 127;
            if (mlive) {
                int cB = __ffs(mlive) - 1; mlive &= mlive - 1;
                int kyB = wave + 16 * cB;
                int cyB = (kyB < 64) ? kyB : kyB - 128;
                int b2B = kx2 + cyB * cyB;
                int cB0 = (lane + kyB) & 127, cB1 = (lane + 64 + kyB) & 127;
                cplx u0[4], u1[4];
                u0[0] = unpack_f8(tile[0][kyA][cA0]); u1[0] = unpack_f8(tile[0][kyA][cA1]);
                u0[1] = unpack_f8(tile[1][kyA][cA0]); u1[1] = unpack_f8(tile[1][kyA][cA1]);
                u0[2] = unpack_f8(tile[0][kyB][cB0]); u1[2] = unpack_f8(tile[0][kyB][cB1]);
                u0[3] = unpack_f8(tile[1][kyB][cB0]); u1[3] = unpack_f8(tile[1][kyB][cB1]);
                fft128v<4>(u0, u1, w, lane);
                acc_pt(accn, accp, accq, b2A + z20, u0[0], u0[1]);
                acc_pt(accn, accp, accq, b2A + z21, u1[0], u1[1]);
                acc_pt(accn, accp, accq, b2B + z20, u0[2], u0[3]);
                acc_pt(accn, accp, accq, b2B + z21, u1[2], u1[3]);
            } else {
                cplx u0[2], u1[2];
                u0[0] = unpack_f8(tile[0][kyA][cA0]); u1[0] = unpack_f8(tile[0][kyA][cA1]);
                u0[1] = unpack_f8(tile[1][kyA][cA0]); u1[1] = unpack_f8(tile[1][kyA][cA1]);
                fft128v<2>(u0, u1, w, lane);
                acc_pt(accn, accp, accq, b2A + z20, u0[0], u0[1]);
                acc_pt(accn, accp, accq, b2A + z21, u1[0], u1[1]);
            }
        }
        __syncthreads();

        if (tid < NSHELL) {
            // Hermitian mirror weight * 1/256 (undo the x16 amplitude pre-scale)
            float wgt = ((kx == 0 || kx == 64) ? 1.0f : 2.0f) * (1.0f / 256.0f);
            float* g = gacc + (size_t)(b0 + b) * ACC_STRIDE;
            atomicAdd(&g[tid],              wgt * accn[tid]);
            atomicAdd(&g[NSHELL + tid],     wgt * accp[tid]);
            atomicAdd(&g[2 * NSHELL + tid], wgt * accq[tid]);
        }
        if (p + 1 < np) __syncthreads();   // protect acc re-zero + tile reuse
    }
}

// ---------------- Finalize: fsc -> loss scalar -----------------------------
__global__ void finalize_kernel(const float* __restrict__ gacc,
                                float* __restrict__ out)
{
    int lane = threadIdx.x;   // 64 threads, shell = lane+1 (1..64)
    int sh = lane + 1;
    float total = 0.0f;
    #pragma unroll
    for (int b = 0; b < 8; b++) {
        const float* g = gacc + b * ACC_STRIDE;
        float num = g[sh];
        float po  = g[NSHELL + sh];
        float pt  = g[2 * NSHELL + sh];
        float fsc = num / sqrtf(po * pt + 1e-6f);
        fsc = fminf(1.0f, fmaxf(-1.0f, fsc));
        total += fsc;
    }
    #pragma unroll
    for (int off = 32; off; off >>= 1) total += __shfl_down(total, off);
    if (lane == 0) out[0] = 1.0f - total / (64.0f * 8.0f);
}

extern "C" void kernel_launch(void* const* d_in, const int* in_sizes, int n_in,
                              void* d_out, int out_size, void* d_ws, size_t ws_size,
                              hipStream_t stream) {
    const float* in0 = (const float*)d_in[0];   // model_output (8,1,128,128,128)
    const float* in1 = (const float*)d_in[1];   // target
    float* gacc = (float*)d_ws;                 // 8*195 floats
    unsigned long long* wsA = (unsigned long long*)((char*)d_ws + 8192);

    hipMemsetAsync(d_ws, 0, 8 * ACC_STRIDE * sizeof(float), stream);

    size_t avail = (ws_size > 8192) ? ws_size - 8192 : 0;
    size_t per_batch = (size_t)NKX * PLANE * sizeof(unsigned long long);   // ~8.5 MB
    int NB = (int)(avail / per_batch);
    if (NB > 8) NB = 8;
    if (NB < 1) NB = 1;

    // 16 / sqrt(128^3): ortho norm plus x16 amplitude pre-scale so the fp8
    // LDS plane sits in e4m3's sweet spot; shell sums are x256, undone at flush.
    const float scale = 1.1048543456039804e-2f;

    for (int b0 = 0; b0 < 8; b0 += NB) {
        int nb = (8 - b0 < NB) ? (8 - b0) : NB;
        fft_x_pack_kernel<<<dim3(nb * 256), dim3(1024), 0, stream>>>(in0, in1, wsA, b0, scale);
        fft_yz_acc_kernel<<<dim3(nb * 64), dim3(1024), 0, stream>>>(wsA, gacc, nb, b0);
    }
    finalize_kernel<<<dim3(1), dim3(64), 0, stream>>>(gacc, (float*)d_out);
}

// Round 5
// 271.484 us; speedup vs baseline: 1.1070x; 1.1070x over previous
//
#include <hip/hip_runtime.h>
#include <math.h>

#define N 128
#define VOL (N*N*N)            // 2097152
#define PLANE (N*N)            // 16384
#define NKX 65                 // kept x-frequencies 0..64 (Hermitian half)
#define NSHELL 65              // shells 0..64
#define NREP 8                 // shell-bin replicas (split same-address atomics)
#define ACC_STRIDE 195         // 3*65 per batch

// packed complex: .x = re, .y = im. Vector ops lower to v_pk_*_f32.
typedef float cplx __attribute__((ext_vector_type(2)));

__device__ __forceinline__ int rev6(int x) { return (int)(__brev((unsigned)x) >> 26); }

// complex multiply by twiddle w=(c,s): r = a*c + swap(a)*(-s, s)
__device__ __forceinline__ cplx cmulw(cplx a, cplx w) {
    cplx sw = __builtin_shufflevector(a, a, 1, 0);
    return __builtin_elementwise_fma(sw, (cplx){-w.y, w.y}, a * w.x);
}

// ---- cross-lane exchange layer (VALU-pipe, no LDS except xor-4) ----
__device__ __forceinline__ void plswap32(cplx v, cplx& lo, cplx& hi) {
    float ax = v.x, bx = v.x, ay = v.y, by = v.y;
    asm("v_permlane32_swap_b32 %0, %1" : "+v"(ax), "+v"(bx));
    asm("v_permlane32_swap_b32 %0, %1" : "+v"(ay), "+v"(by));
    lo = (cplx){ax, ay}; hi = (cplx){bx, by};
}
__device__ __forceinline__ void plswap16(cplx v, cplx& lo, cplx& hi) {
    float ax = v.x, bx = v.x, ay = v.y, by = v.y;
    asm("v_permlane16_swap_b32 %0, %1" : "+v"(ax), "+v"(bx));
    asm("v_permlane16_swap_b32 %0, %1" : "+v"(ay), "+v"(by));
    lo = (cplx){ax, ay}; hi = (cplx){bx, by};
}
template<int CTRL>
__device__ __forceinline__ cplx dpp_xor(cplx v) {
    int rx = __builtin_amdgcn_mov_dpp(__float_as_int(v.x), CTRL, 0xF, 0xF, true);
    int ry = __builtin_amdgcn_mov_dpp(__float_as_int(v.y), CTRL, 0xF, 0xF, true);
    return (cplx){__int_as_float(rx), __int_as_float(ry)};
}
// h=4: no DPP/permlane pattern for xor4 -> single ds_swizzle on packed bf16
__device__ __forceinline__ cplx swz4(cplx v) {
    unsigned p = __builtin_amdgcn_perm(__float_as_uint(v.y), __float_as_uint(v.x), 0x07060302u);
    unsigned q = (unsigned)__builtin_amdgcn_ds_swizzle((int)p, 0x101F);  // xor 4
    return (cplx){__uint_as_float(q << 16), __uint_as_float(q & 0xFFFF0000u)};
}

// bf16x2 pack (RNE) / unpack: complex value in one uint (re low, im high)
__device__ __forceinline__ unsigned int pack_bf2(cplx v) {
    unsigned int r = __float_as_uint(v.x);
    unsigned int i = __float_as_uint(v.y);
    r = (r + 0x7FFFu + ((r >> 16) & 1u)) >> 16;
    i = (i + 0x7FFFu + ((i >> 16) & 1u)) & 0xFFFF0000u;
    return i | r;
}
__device__ __forceinline__ cplx unpack_bf2(unsigned int u) {
    return (cplx){__uint_as_float(u << 16), __uint_as_float(u & 0xFFFF0000u)};
}

// fp8 e4m3 packed complex (re byte0, im byte1) for the in-LDS plane
__device__ __forceinline__ unsigned short pack_f8(cplx v) {
    int p = __builtin_amdgcn_cvt_pk_fp8_f32(v.x, v.y, 0, false);
    return (unsigned short)(p & 0xFFFF);
}
__device__ __forceinline__ cplx unpack_f8(unsigned short u) {
    auto r = __builtin_amdgcn_cvt_pk_f32_fp8((int)u, false);
    return (cplx){r[0], r[1]};
}

// 64-entry twiddle table W[m] = e^{-2*pi*i*m/128}, built once per block
__device__ __forceinline__ void build_W(cplx* Wsh, int tid) {
    if (tid < 64) {
        float s, c;
        sincosf(-6.283185307179586f * (float)tid / 128.0f, &s, &c);
        Wsh[tid] = (cplx){c, s};
    }
}

struct TwE { cplx w128; cplx we[5]; };

__device__ __forceinline__ TwE make_twe(const cplx* Wsh, int lane) {
    TwE w;
    w.w128 = Wsh[lane];
    #pragma unroll
    for (int i = 0; i < 5; i++) {
        int h = 32 >> i;
        cplx t = Wsh[(lane & (h - 1)) << (i + 1)];
        w.we[i] = (lane & h) ? t : (cplx){1.0f, 0.0f};
    }
    return w;
}

__device__ __forceinline__ void bstage(cplx& v, cplx o, float s, cplx we) {
    cplx t = __builtin_elementwise_fma((cplx){s, s}, v, o);
    v = cmulw(t, we);
}
__device__ __forceinline__ void bstage_lh(cplx& v, cplx lo, cplx hi, float s, cplx we) {
    cplx t = __builtin_elementwise_fma((cplx){s, s}, hi, lo);
    v = cmulw(t, we);
}

// Two independent 128-pt DIF FFTs (4 chains). 5 of 6 cross-lane stages on the
// VALU pipe (permlane_swap / DPP, fp32 exact); only xor-4 uses one ds_swizzle
// per complex (packed bf16). K=2 fixed: proven spill-free register footprint.
// Pair A: lane holds a0=x[lane], a1=x[lane+64]; same for pair B.
// Output: a0 = X[2*rev6(lane)], a1 = X[2*rev6(lane)+1].
__device__ __forceinline__ void fft128x2(cplx& a0, cplx& a1,
                                         cplx& b0, cplx& b1,
                                         const TwE& w, int lane) {
    cplx d;
    d  = a0 - a1;
    a0 = a0 + a1;
    a1 = cmulw(d, w.w128);
    d  = b0 - b1;
    b0 = b0 + b1;
    b1 = cmulw(d, w.w128);

    {   // h = 32 : permlane32_swap
        float s = (lane & 32) ? -1.0f : 1.0f;
        cplx l0, h0, l1, h1, l2, h2, l3, h3;
        plswap32(a0, l0, h0); plswap32(a1, l1, h1);
        plswap32(b0, l2, h2); plswap32(b1, l3, h3);
        bstage_lh(a0, l0, h0, s, w.we[0]);
        bstage_lh(a1, l1, h1, s, w.we[0]);
        bstage_lh(b0, l2, h2, s, w.we[0]);
        bstage_lh(b1, l3, h3, s, w.we[0]);
    }
    {   // h = 16 : permlane16_swap
        float s = (lane & 16) ? -1.0f : 1.0f;
        cplx l0, h0, l1, h1, l2, h2, l3, h3;
        plswap16(a0, l0, h0); plswap16(a1, l1, h1);
        plswap16(b0, l2, h2); plswap16(b1, l3, h3);
        bstage_lh(a0, l0, h0, s, w.we[1]);
        bstage_lh(a1, l1, h1, s, w.we[1]);
        bstage_lh(b0, l2, h2, s, w.we[1]);
        bstage_lh(b1, l3, h3, s, w.we[1]);
    }
    {   // h = 8 : DPP row_ror:8
        float s = (lane & 8) ? -1.0f : 1.0f;
        cplx o0 = dpp_xor<0x128>(a0), o1 = dpp_xor<0x128>(a1);
        cplx o2 = dpp_xor<0x128>(b0), o3 = dpp_xor<0x128>(b1);
        bstage(a0, o0, s, w.we[2]); bstage(a1, o1, s, w.we[2]);
        bstage(b0, o2, s, w.we[2]); bstage(b1, o3, s, w.we[2]);
    }
    {   // h = 4 : single LDS swizzle stage (packed bf16)
        float s = (lane & 4) ? -1.0f : 1.0f;
        cplx o0 = swz4(a0), o1 = swz4(a1), o2 = swz4(b0), o3 = swz4(b1);
        bstage(a0, o0, s, w.we[3]); bstage(a1, o1, s, w.we[3]);
        bstage(b0, o2, s, w.we[3]); bstage(b1, o3, s, w.we[3]);
    }
    {   // h = 2 : DPP quad_perm [2,3,0,1]
        float s = (lane & 2) ? -1.0f : 1.0f;
        cplx o0 = dpp_xor<0x4E>(a0), o1 = dpp_xor<0x4E>(a1);
        cplx o2 = dpp_xor<0x4E>(b0), o3 = dpp_xor<0x4E>(b1);
        bstage(a0, o0, s, w.we[4]); bstage(a1, o1, s, w.we[4]);
        bstage(b0, o2, s, w.we[4]); bstage(b1, o3, s, w.we[4]);
    }
    {   // h = 1 : DPP quad_perm [1,0,3,2], final butterfly (no twiddle)
        float s = (lane & 1) ? -1.0f : 1.0f;
        cplx o0 = dpp_xor<0xB1>(a0), o1 = dpp_xor<0xB1>(a1);
        cplx o2 = dpp_xor<0xB1>(b0), o3 = dpp_xor<0xB1>(b1);
        cplx sv = (cplx){s, s};
        a0 = __builtin_elementwise_fma(sv, a0, o0);
        a1 = __builtin_elementwise_fma(sv, a1, o1);
        b0 = __builtin_elementwise_fma(sv, b0, o2);
        b1 = __builtin_elementwise_fma(sv, b1, o3);
    }
}

// slot index holding frequency k after fft128
__device__ __forceinline__ int slot_of(int k) {
    return (k & 1) ? 64 + rev6(k >> 1) : rev6(k >> 1);
}

// ---- Pass 1: packed x-FFT (L = mo + i*tg), Hermitian unpack, keep kx=0..64 ----
// grid: nb*128(z)*2(ytile) blocks of 1024 (16 waves, 64 y-lines per block).
// Workspace element = uint64 {O:bf16x2 | T:bf16x2 << 32} at [b][kx][z][y]:
// one dwordx2 store per point (512B runs per kx); pass 2 fetches a whole
// fft128x2 input pair with one dwordx2 load.
__global__ __launch_bounds__(1024, 8)
void fft_x_pack_kernel(const float* __restrict__ in0, const float* __restrict__ in1,
                       unsigned long long* __restrict__ ws, int b0, float scale)
{
    __shared__ cplx tile[64][129];
    __shared__ cplx Wsh[64];
    int tid = threadIdx.x, lane = tid & 63, wave = tid >> 6;
    int bi = blockIdx.x;
    int yt = bi & 1, z = (bi >> 1) & 127, b = bi >> 8;
    build_W(Wsh, tid);
    __syncthreads();
    TwE w = make_twe(Wsh, lane);

    size_t src_base = (size_t)(b0 + b) * VOL + (size_t)z * PLANE;
    #pragma unroll
    for (int c = 0; c < 4; c += 2) {
        int j0 = wave * 4 + c, j1 = j0 + 1;
        const float* pa0 = in0 + src_base + (size_t)(yt * 64 + j0) * N;
        const float* pa1 = in1 + src_base + (size_t)(yt * 64 + j0) * N;
        const float* pb0 = in0 + src_base + (size_t)(yt * 64 + j1) * N;
        const float* pb1 = in1 + src_base + (size_t)(yt * 64 + j1) * N;
        cplx a0 = (cplx){pa0[lane]      * scale, pa1[lane]      * scale};
        cplx a1 = (cplx){pa0[lane + 64] * scale, pa1[lane + 64] * scale};
        cplx c0 = (cplx){pb0[lane]      * scale, pb1[lane]      * scale};
        cplx c1 = (cplx){pb0[lane + 64] * scale, pb1[lane + 64] * scale};
        fft128x2(a0, a1, c0, c1, w, lane);
        tile[j0][lane]      = a0;
        tile[j0][lane + 64] = a1;
        tile[j1][lane]      = c0;
        tile[j1][lane + 64] = c1;
    }
    __syncthreads();

    // unpack: O = (L(k)+conj(L(-k)))/2 ; T = (L(k)-conj(L(-k)))/(2i)
    // j spans 64 consecutive y per wave -> 512B store runs.
    size_t dst_off = (size_t)b * NKX * PLANE + (size_t)z * N + yt * 64;
    for (int idx = tid; idx < NKX * 64; idx += 1024) {
        int j  = idx & 63;
        int kx = idx >> 6;               // wave-uniform (waves are 64-aligned)
        int mk = (128 - kx) & 127;
        cplx a  = tile[j][slot_of(kx)];
        cplx bm = tile[j][slot_of(mk)];
        cplx O = (cplx){0.5f * (a.x + bm.x), 0.5f * (a.y - bm.y)};
        cplx T = (cplx){0.5f * (a.y + bm.y), 0.5f * (bm.x - a.x)};
        ws[dst_off + (size_t)kx * PLANE + j] =
            ((unsigned long long)pack_bf2(T) << 32) | (unsigned long long)pack_bf2(O);
    }
}

// ---- Fused pass 2: y-FFT + z-FFT + shell accumulation per (b, kx) plane ----
// grid: nb*64 blocks of 1024 (16 waves); 2 blocks/CU * 256 CUs at nb=8 -> no
// tail. Complementary plane pairing: kslot<32 -> kx=kslot (heavy planes),
// kslot 33..63 -> kx=95-kslot (light planes), kslot 32 -> kx=63 AND 64. Under
// round-robin block->CU assignment (c, c+256 share a CU) each CU gets one
// heavy + one light plane, flattening the end-of-grid tail.
// Shell bins are 8-way replicated (replica = rev6(lane)&7): consecutive kz
// land in different replicas, splitting the same-address atomic serialization.
// LDS plane as fp8x2 (values x16 from pass1's scale; shell sums x256,
// undone at flush). Swizzle col = (z + ky) & 127.
__global__ __launch_bounds__(1024, 8)
void fft_yz_acc_kernel(const unsigned long long* __restrict__ ws, float* __restrict__ gacc,
                       int nb, int b0)
{
    __shared__ unsigned short tile[2][128][128];   // 65536 B
    __shared__ cplx Wsh[64];
    __shared__ float accn[NREP][NSHELL], accp[NREP][NSHELL], accq[NREP][NSHELL];
    int tid = threadIdx.x, lane = tid & 63, wave = tid >> 6;
    int bi = blockIdx.x;
    int kslot = bi / nb;              // 0..63
    int b = bi - kslot * nb;
    int np = (kslot == 32) ? 2 : 1;
    int kxbase = (kslot < 32) ? kslot : (95 - kslot);   // kslot 32 -> 63 (+p)

    build_W(Wsh, tid);
    __syncthreads();
    TwE w = make_twe(Wsh, lane);

    int m6  = rev6(lane);
    int rep = m6 & (NREP - 1);
    int kz0 = 2 * m6, kz1 = kz0 + 1;
    int cz0 = (kz0 < 64) ? kz0 : kz0 - 128;
    int cz1 = (kz1 < 64) ? kz1 : kz1 - 128;
    int z20 = cz0 * cz0, z21 = cz1 * cz1;

    for (int p = 0; p < np; p++) {
        int kx = kxbase + p;
        {   // zero the replicated bins
            float* an = &accn[0][0];
            float* ap = &accp[0][0];
            float* aq = &accq[0][0];
            for (int i = tid; i < NREP * NSHELL; i += 1024) { an[i] = 0.0f; ap[i] = 0.0f; aq[i] = 0.0f; }
        }
        __syncthreads();

        // Phase A: 128 z-lines, each u64 carrying {O,T}; wave handles 8,
        // one-step register prefetch to hide the HBM latency under the FFT.
        const unsigned long long* pz = ws + ((size_t)b * NKX + kx) * PLANE + (size_t)(wave * 8) * N;
        unsigned long long v0 = pz[lane];
        unsigned long long v1 = pz[lane + 64];
        for (int c = 0; c < 8; c++) {
            unsigned long long n0 = 0, n1 = 0;
            if (c < 7) {   // prefetch next line (wave-uniform branch)
                n0 = pz[(size_t)(c + 1) * N + lane];
                n1 = pz[(size_t)(c + 1) * N + lane + 64];
            }
            cplx a0 = unpack_bf2((unsigned)v0);
            cplx a1 = unpack_bf2((unsigned)v1);
            cplx t0 = unpack_bf2((unsigned)(v0 >> 32));
            cplx t1 = unpack_bf2((unsigned)(v1 >> 32));
            fft128x2(a0, a1, t0, t1, w, lane);
            int z0 = wave * 8 + c;
            int ky0 = 2 * m6;                        // a1/t1 hold ky0+1
            tile[0][ky0    ][(z0 + ky0    ) & 127] = pack_f8(a0);
            tile[0][ky0 + 1][(z0 + ky0 + 1) & 127] = pack_f8(a1);
            tile[1][ky0    ][(z0 + ky0    ) & 127] = pack_f8(t0);
            tile[1][ky0 + 1][(z0 + ky0 + 1) & 127] = pack_f8(t1);
            v0 = n0; v1 = n1;
        }
        __syncthreads();

        // Phase B: z-FFT per live ky line (o and t interleaved) + accumulate
        int kx2 = kx * kx;
        for (int c = 0; c < 8; c++) {
            int ky = wave + 16 * c;
            int cy = (ky < 64) ? ky : ky - 128;
            int base2 = kx2 + cy * cy;
            if (base2 > 4224) continue;              // whole z-line outside sphere
            int c0 = (lane + ky) & 127;
            int c1 = (lane + 64 + ky) & 127;
            cplx o0 = unpack_f8(tile[0][ky][c0]);
            cplx o1 = unpack_f8(tile[0][ky][c1]);
            cplx t0 = unpack_f8(tile[1][ky][c0]);
            cplx t1 = unpack_f8(tile[1][ky][c1]);
            fft128x2(o0, o1, t0, t1, w, lane);
            int r20 = base2 + z20;
            if (r20 <= 4224) {
                int sh = (int)sqrtf((float)r20);
                if ((sh + 1) * (sh + 1) <= r20) sh++;
                else if (sh * sh > r20) sh--;
                atomicAdd(&accn[rep][sh], o0.x * t0.x + o0.y * t0.y);
                atomicAdd(&accp[rep][sh], o0.x * o0.x + o0.y * o0.y);
                atomicAdd(&accq[rep][sh], t0.x * t0.x + t0.y * t0.y);
            }
            int r21 = base2 + z21;
            if (r21 <= 4224) {
                int sh = (int)sqrtf((float)r21);
                if ((sh + 1) * (sh + 1) <= r21) sh++;
                else if (sh * sh > r21) sh--;
                atomicAdd(&accn[rep][sh], o1.x * t1.x + o1.y * t1.y);
                atomicAdd(&accp[rep][sh], o1.x * o1.x + o1.y * o1.y);
                atomicAdd(&accq[rep][sh], t1.x * t1.x + t1.y * t1.y);
            }
        }
        __syncthreads();

        if (tid < NSHELL) {
            float sn = 0.0f, sp = 0.0f, sq = 0.0f;
            #pragma unroll
            for (int r = 0; r < NREP; r++) { sn += accn[r][tid]; sp += accp[r][tid]; sq += accq[r][tid]; }
            // Hermitian mirror weight * 1/256 (undo the x16 amplitude pre-scale)
            float wgt = ((kx == 0 || kx == 64) ? 1.0f : 2.0f) * (1.0f / 256.0f);
            float* g = gacc + (size_t)(b0 + b) * ACC_STRIDE;
            atomicAdd(&g[tid],              wgt * sn);
            atomicAdd(&g[NSHELL + tid],     wgt * sp);
            atomicAdd(&g[2 * NSHELL + tid], wgt * sq);
        }
        if (p + 1 < np) __syncthreads();   // protect bin re-zero + tile reuse
    }
}

// ---------------- Finalize: fsc -> loss scalar -----------------------------
__global__ void finalize_kernel(const float* __restrict__ gacc,
                                float* __restrict__ out)
{
    int lane = threadIdx.x;   // 64 threads, shell = lane+1 (1..64)
    int sh = lane + 1;
    float total = 0.0f;
    #pragma unroll
    for (int b = 0; b < 8; b++) {
        const float* g = gacc + b * ACC_STRIDE;
        float num = g[sh];
        float po  = g[NSHELL + sh];
        float pt  = g[2 * NSHELL + sh];
        float fsc = num / sqrtf(po * pt + 1e-6f);
        fsc = fminf(1.0f, fmaxf(-1.0f, fsc));
        total += fsc;
    }
    #pragma unroll
    for (int off = 32; off; off >>= 1) total += __shfl_down(total, off);
    if (lane == 0) out[0] = 1.0f - total / (64.0f * 8.0f);
}

extern "C" void kernel_launch(void* const* d_in, const int* in_sizes, int n_in,
                              void* d_out, int out_size, void* d_ws, size_t ws_size,
                              hipStream_t stream) {
    const float* in0 = (const float*)d_in[0];   // model_output (8,1,128,128,128)
    const float* in1 = (const float*)d_in[1];   // target
    float* gacc = (float*)d_ws;                 // 8*195 floats
    unsigned long long* wsA = (unsigned long long*)((char*)d_ws + 8192);

    hipMemsetAsync(d_ws, 0, 8 * ACC_STRIDE * sizeof(float), stream);

    size_t avail = (ws_size > 8192) ? ws_size - 8192 : 0;
    size_t per_batch = (size_t)NKX * PLANE * sizeof(unsigned long long);   // ~8.5 MB
    int NB = (int)(avail / per_batch);
    if (NB > 8) NB = 8;
    if (NB < 1) NB = 1;

    // 16 / sqrt(128^3): ortho norm plus x16 amplitude pre-scale so the fp8
    // LDS plane sits in e4m3's sweet spot; shell sums are x256, undone at flush.
    const float scale = 1.1048543456039804e-2f;

    for (int b0 = 0; b0 < 8; b0 += NB) {
        int nb = (8 - b0 < NB) ? (8 - b0) : NB;
        fft_x_pack_kernel<<<dim3(nb * 256), dim3(1024), 0, stream>>>(in0, in1, wsA, b0, scale);
        fft_yz_acc_kernel<<<dim3(nb * 64), dim3(1024), 0, stream>>>(wsA, gacc, nb, b0);
    }
    finalize_kernel<<<dim3(1), dim3(64), 0, stream>>>(gacc, (float*)d_out);
}